// Round 1
// baseline (2792.264 us; speedup 1.0000x reference)
//
#include <hip/hip_runtime.h>
#include <hip/hip_bf16.h>

#define N_NODES 100000
#define N_EDGES 1600000
#define D 128
#define TILES (N_NODES / 16)   // 6250 row-tiles of 16
#define WPB 8                  // waves per block in fused kernel

typedef __attribute__((ext_vector_type(4))) float f32x4;
typedef __attribute__((ext_vector_type(8))) short short8;

// f32 -> bf16 round-to-nearest-even
static __device__ __forceinline__ unsigned short f2bf(float f) {
  unsigned u = __float_as_uint(f);
  u += 0x7fffu + ((u >> 16) & 1u);
  return (unsigned short)(u >> 16);
}

// Phase B: edge-parallel mean-scatter. 32 lanes per edge, float4 per lane.
// sums == d_out (reused as the accumulation buffer).
__global__ __launch_bounds__(256) void scatter_k(
    const float* __restrict__ x, const int* __restrict__ ei,
    float* __restrict__ sums, int* __restrict__ cnt) {
  int t = blockIdx.x * 256 + threadIdx.x;
  int e = t >> 5;
  if (e >= N_EDGES) return;
  int lane = t & 31;
  int src = ei[e];            // row 0 of edge_index: message sources
  int dst = ei[N_EDGES + e];  // row 1: aggregation targets
  f32x4 v = *(const f32x4*)(x + (size_t)src * D + lane * 4);
  float* o = sums + (size_t)dst * D + lane * 4;
  atomicAdd(o + 0, v[0]);
  atomicAdd(o + 1, v[1]);
  atomicAdd(o + 2, v[2]);
  atomicAdd(o + 3, v[3]);
  if (lane == 0) atomicAdd(cnt + dst, 1);
}

// Phase C: out = normalize( [sums*inv | x] @ [W_l; W_r] + b_l ), bf16 MFMA.
// W (256x128) staged once per block into LDS as bf16, [col][k] layout,
// XOR-swizzled 16B chunks to avoid 512B-stride bank conflicts on ds_read_b128.
__global__ __launch_bounds__(512) void fused_k(
    const float* __restrict__ x, const float* __restrict__ Wl,
    const float* __restrict__ bl, const float* __restrict__ Wr,
    const int* __restrict__ cnt, float* __restrict__ out /* in: sums, out: result */) {
  __shared__ unsigned short Wt[128 * 256];  // 64 KiB

  int tid = threadIdx.x;
  // Stage + transpose + bf16-convert W. k-major loop keeps global reads coalesced.
  for (int i = tid; i < 128 * 256; i += 512) {
    int k = i >> 7;       // 0..255 (0..127 = W_l rows, 128..255 = W_r rows)
    int c = i & 127;      // output column
    float w = (k < 128) ? Wl[k * 128 + c] : Wr[(k - 128) * 128 + c];
    int phys = (k >> 3) ^ (c & 7);  // swizzle 16B chunk index within the row
    Wt[c * 256 + (phys << 3) + (k & 7)] = f2bf(w);
  }
  __syncthreads();

  int tile = blockIdx.x * WPB + (tid >> 6);
  if (tile >= TILES) return;
  int lane = tid & 63;
  int c0 = lane & 15;  // A-row within tile / D-column-within-16
  int g = lane >> 4;   // k-group selector
  int row0 = tile * 16;

  float cv = (float)cnt[row0 + c0];
  float inv = 1.0f / fmaxf(cv, 1.0f);

  f32x4 acc[8];
  #pragma unroll
  for (int ct = 0; ct < 8; ct++)
    for (int j = 0; j < 4; j++) acc[ct][j] = 0.0f;

  #pragma unroll
  for (int kf = 0; kf < 8; kf++) {
    // kf 0..3: mean part (k 0..127, W_l); kf 4..7: x part (k 128..255, W_r)
    const float* a_src = (kf < 4) ? out : x;
    float s = (kf < 4) ? inv : 1.0f;
    int koff = (kf & 3) * 32 + g * 8;
    const float* p = a_src + (size_t)(row0 + c0) * D + koff;
    f32x4 v0 = *(const f32x4*)p;
    f32x4 v1 = *(const f32x4*)(p + 4);
    short8 af;
    af[0] = (short)f2bf(v0[0] * s);
    af[1] = (short)f2bf(v0[1] * s);
    af[2] = (short)f2bf(v0[2] * s);
    af[3] = (short)f2bf(v0[3] * s);
    af[4] = (short)f2bf(v1[0] * s);
    af[5] = (short)f2bf(v1[1] * s);
    af[6] = (short)f2bf(v1[2] * s);
    af[7] = (short)f2bf(v1[3] * s);
    #pragma unroll
    for (int ct = 0; ct < 8; ct++) {
      int c = ct * 16 + c0;
      short8 bf = *(const short8*)&Wt[c * 256 + ((((kf << 2) + g) ^ (c & 7)) << 3)];
      acc[ct] = __builtin_amdgcn_mfma_f32_16x16x32_bf16(af, bf, acc[ct], 0, 0, 0);
    }
  }

  // Epilogue: + bias, row L2-normalize (D layout: col = lane&15, row = g*4+j).
  float ss[4] = {0.f, 0.f, 0.f, 0.f};
  #pragma unroll
  for (int ct = 0; ct < 8; ct++) {
    float bias = bl[ct * 16 + c0];
    #pragma unroll
    for (int j = 0; j < 4; j++) {
      float v = acc[ct][j] + bias;
      acc[ct][j] = v;
      ss[j] += v * v;
    }
  }
  #pragma unroll
  for (int j = 0; j < 4; j++) {
    float s = ss[j];
    s += __shfl_xor(s, 1);
    s += __shfl_xor(s, 2);
    s += __shfl_xor(s, 4);
    s += __shfl_xor(s, 8);
    ss[j] = 1.0f / fmaxf(sqrtf(s), 1e-12f);
  }
  #pragma unroll
  for (int ct = 0; ct < 8; ct++) {
    #pragma unroll
    for (int j = 0; j < 4; j++) {
      out[(size_t)(row0 + g * 4 + j) * D + ct * 16 + c0] = acc[ct][j] * ss[j];
    }
  }
}

extern "C" void kernel_launch(void* const* d_in, const int* in_sizes, int n_in,
                              void* d_out, int out_size, void* d_ws, size_t ws_size,
                              hipStream_t stream) {
  const float* x  = (const float*)d_in[0];
  const int*   ei = (const int*)d_in[1];
  const float* Wl = (const float*)d_in[2];
  const float* bl = (const float*)d_in[3];
  const float* Wr = (const float*)d_in[4];
  float* out = (float*)d_out;
  int* cnt = (int*)d_ws;

  hipMemsetAsync(d_out, 0, (size_t)out_size * sizeof(float), stream);
  hipMemsetAsync(cnt, 0, N_NODES * sizeof(int), stream);

  // 32 threads per edge -> 51.2M threads / 256 = 200000 blocks
  scatter_k<<<(N_EDGES * 32) / 256, 256, 0, stream>>>(x, ei, out, cnt);
  fused_k<<<(TILES + WPB - 1) / WPB, 512, 0, stream>>>(x, Wl, bl, Wr, cnt, out);
}

// Round 2
// 370.269 us; speedup vs baseline: 7.5412x; 7.5412x over previous
//
#include <hip/hip_runtime.h>
#include <hip/hip_bf16.h>

#define N_NODES 100000
#define N_EDGES 1600000
#define D 128
#define TILES (N_NODES / 16)   // 6250 row-tiles of 16
#define WPB 8                  // waves per block in fused kernel
#define NB 391                 // ceil(100000/256) scan blocks

typedef __attribute__((ext_vector_type(4))) float f32x4;
typedef __attribute__((ext_vector_type(2))) float f32x2;
typedef __attribute__((ext_vector_type(8))) short short8;

// f32 -> bf16 round-to-nearest-even
static __device__ __forceinline__ unsigned short f2bf(float f) {
  unsigned u = __float_as_uint(f);
  u += 0x7fffu + ((u >> 16) & 1u);
  return (unsigned short)(u >> 16);
}

// ---- Phase A1: histogram of dst ----
__global__ __launch_bounds__(256) void hist_k(const int* __restrict__ ei,
                                              int* __restrict__ cnt) {
  int e = blockIdx.x * 256 + threadIdx.x;
  if (e >= N_EDGES) return;
  atomicAdd(&cnt[ei[N_EDGES + e]], 1);
}

// ---- Phase A2: 3-step exclusive scan of cnt -> ptr (and wr copy) ----
__global__ __launch_bounds__(256) void scan_blk(const int* __restrict__ cnt,
                                                int* __restrict__ bsum) {
  __shared__ int s[256];
  int i = blockIdx.x * 256 + threadIdx.x;
  s[threadIdx.x] = (i < N_NODES) ? cnt[i] : 0;
  __syncthreads();
  for (int o = 128; o > 0; o >>= 1) {
    if (threadIdx.x < o) s[threadIdx.x] += s[threadIdx.x + o];
    __syncthreads();
  }
  if (threadIdx.x == 0) bsum[blockIdx.x] = s[0];
}

__global__ __launch_bounds__(512) void scan_top(const int* __restrict__ bsum,
                                                int* __restrict__ boff) {
  __shared__ int s[512];
  int v = (threadIdx.x < NB) ? bsum[threadIdx.x] : 0;
  s[threadIdx.x] = v;
  __syncthreads();
  for (int o = 1; o < 512; o <<= 1) {
    int t = (threadIdx.x >= o) ? s[threadIdx.x - o] : 0;
    __syncthreads();
    s[threadIdx.x] += t;
    __syncthreads();
  }
  if (threadIdx.x < NB) boff[threadIdx.x] = s[threadIdx.x] - v;  // exclusive
}

__global__ __launch_bounds__(256) void scan_fin(const int* __restrict__ cnt,
                                                const int* __restrict__ boff,
                                                int* __restrict__ ptr,
                                                int* __restrict__ wr) {
  __shared__ int s[256];
  int i = blockIdx.x * 256 + threadIdx.x;
  int v = (i < N_NODES) ? cnt[i] : 0;
  s[threadIdx.x] = v;
  __syncthreads();
  for (int o = 1; o < 256; o <<= 1) {
    int t = (threadIdx.x >= o) ? s[threadIdx.x - o] : 0;
    __syncthreads();
    s[threadIdx.x] += t;
    __syncthreads();
  }
  if (i < N_NODES) {
    int ex = s[threadIdx.x] - v + boff[blockIdx.x];
    ptr[i] = ex;
    wr[i] = ex;
  }
}

// ---- Phase A3: fill CSR (edge src ids bucketed by dst) ----
__global__ __launch_bounds__(256) void fill_k(const int* __restrict__ ei,
                                              int* __restrict__ wr,
                                              int* __restrict__ csr) {
  int e = blockIdx.x * 256 + threadIdx.x;
  if (e >= N_EDGES) return;
  int dst = ei[N_EDGES + e];
  int pos = atomicAdd(&wr[dst], 1);
  csr[pos] = ei[e];
}

// ---- Phase B: per-node gather-sum (atomic-free). 1 wave per node. ----
__global__ __launch_bounds__(256) void gather_k(const float* __restrict__ x,
                                                const int* __restrict__ csr,
                                                const int* __restrict__ ptr,
                                                const int* __restrict__ cnt,
                                                float* __restrict__ sums) {
  int node = blockIdx.x * 4 + (threadIdx.x >> 6);
  if (node >= N_NODES) return;
  int lane = threadIdx.x & 63;
  int base = ptr[node];
  int deg = cnt[node];
  float a0 = 0.0f, a1 = 0.0f;
  for (int c = 0; c < deg; c += 64) {
    int n = min(64, deg - c);
    int eidx = (c + lane < deg) ? csr[base + c + lane] : 0;
    #pragma unroll 4
    for (int j = 0; j < n; j++) {
      int src = __shfl(eidx, j);
      f32x2 v = *(const f32x2*)(x + (size_t)src * D + lane * 2);
      a0 += v[0];
      a1 += v[1];
    }
  }
  f32x2 r;
  r[0] = a0;
  r[1] = a1;
  *(f32x2*)(sums + (size_t)node * D + lane * 2) = r;
}

// ---- Phase C: out = normalize( [sums*inv | x] @ [W_l; W_r] + b_l ), bf16 MFMA ----
__global__ __launch_bounds__(512) void fused_k(
    const float* __restrict__ x, const float* __restrict__ Wl,
    const float* __restrict__ bl, const float* __restrict__ Wr,
    const int* __restrict__ cnt, float* __restrict__ out /* in: sums, out: result */) {
  __shared__ unsigned short Wt[128 * 256];  // 64 KiB

  int tid = threadIdx.x;
  for (int i = tid; i < 128 * 256; i += 512) {
    int k = i >> 7;       // 0..255 (0..127 = W_l rows, 128..255 = W_r rows)
    int c = i & 127;      // output column
    float w = (k < 128) ? Wl[k * 128 + c] : Wr[(k - 128) * 128 + c];
    int phys = (k >> 3) ^ (c & 7);  // swizzle 16B chunk index within the row
    Wt[c * 256 + (phys << 3) + (k & 7)] = f2bf(w);
  }
  __syncthreads();

  int tile = blockIdx.x * WPB + (tid >> 6);
  if (tile >= TILES) return;
  int lane = tid & 63;
  int c0 = lane & 15;  // A-row within tile / D-column-within-16
  int g = lane >> 4;   // k-group selector
  int row0 = tile * 16;

  float cv = (float)cnt[row0 + c0];
  float inv = 1.0f / fmaxf(cv, 1.0f);

  f32x4 acc[8];
  #pragma unroll
  for (int ct = 0; ct < 8; ct++)
    for (int j = 0; j < 4; j++) acc[ct][j] = 0.0f;

  #pragma unroll
  for (int kf = 0; kf < 8; kf++) {
    // kf 0..3: mean part (k 0..127, W_l); kf 4..7: x part (k 128..255, W_r)
    const float* a_src = (kf < 4) ? out : x;
    float s = (kf < 4) ? inv : 1.0f;
    int koff = (kf & 3) * 32 + g * 8;
    const float* p = a_src + (size_t)(row0 + c0) * D + koff;
    f32x4 v0 = *(const f32x4*)p;
    f32x4 v1 = *(const f32x4*)(p + 4);
    short8 af;
    af[0] = (short)f2bf(v0[0] * s);
    af[1] = (short)f2bf(v0[1] * s);
    af[2] = (short)f2bf(v0[2] * s);
    af[3] = (short)f2bf(v0[3] * s);
    af[4] = (short)f2bf(v1[0] * s);
    af[5] = (short)f2bf(v1[1] * s);
    af[6] = (short)f2bf(v1[2] * s);
    af[7] = (short)f2bf(v1[3] * s);
    #pragma unroll
    for (int ct = 0; ct < 8; ct++) {
      int c = ct * 16 + c0;
      short8 bf = *(const short8*)&Wt[c * 256 + ((((kf << 2) + g) ^ (c & 7)) << 3)];
      acc[ct] = __builtin_amdgcn_mfma_f32_16x16x32_bf16(af, bf, acc[ct], 0, 0, 0);
    }
  }

  // Epilogue: + bias, row L2-normalize (D layout: col = lane&15, row = g*4+j).
  float ss[4] = {0.f, 0.f, 0.f, 0.f};
  #pragma unroll
  for (int ct = 0; ct < 8; ct++) {
    float bias = bl[ct * 16 + c0];
    #pragma unroll
    for (int j = 0; j < 4; j++) {
      float v = acc[ct][j] + bias;
      acc[ct][j] = v;
      ss[j] += v * v;
    }
  }
  #pragma unroll
  for (int j = 0; j < 4; j++) {
    float s = ss[j];
    s += __shfl_xor(s, 1);
    s += __shfl_xor(s, 2);
    s += __shfl_xor(s, 4);
    s += __shfl_xor(s, 8);
    ss[j] = 1.0f / fmaxf(sqrtf(s), 1e-12f);
  }
  #pragma unroll
  for (int ct = 0; ct < 8; ct++) {
    #pragma unroll
    for (int j = 0; j < 4; j++) {
      out[(size_t)(row0 + g * 4 + j) * D + ct * 16 + c0] = acc[ct][j] * ss[j];
    }
  }
}

extern "C" void kernel_launch(void* const* d_in, const int* in_sizes, int n_in,
                              void* d_out, int out_size, void* d_ws, size_t ws_size,
                              hipStream_t stream) {
  const float* x  = (const float*)d_in[0];
  const int*   ei = (const int*)d_in[1];
  const float* Wl = (const float*)d_in[2];
  const float* bl = (const float*)d_in[3];
  const float* Wr = (const float*)d_in[4];
  float* out = (float*)d_out;

  // Workspace layout (int elements)
  int* w = (int*)d_ws;
  int* cnt  = w;             // 100000
  int* ptr  = w + 100000;    // 100000
  int* wr   = w + 200000;    // 100000
  int* bsum = w + 300000;    // 391
  int* boff = w + 300512;    // 391
  int* csr  = w + 301056;    // 1600000  (total ~7.6 MB)

  hipMemsetAsync(cnt, 0, N_NODES * sizeof(int), stream);

  hist_k<<<(N_EDGES + 255) / 256, 256, 0, stream>>>(ei, cnt);
  scan_blk<<<NB, 256, 0, stream>>>(cnt, bsum);
  scan_top<<<1, 512, 0, stream>>>(bsum, boff);
  scan_fin<<<NB, 256, 0, stream>>>(cnt, boff, ptr, wr);
  fill_k<<<(N_EDGES + 255) / 256, 256, 0, stream>>>(ei, wr, csr);
  gather_k<<<(N_NODES + 3) / 4, 256, 0, stream>>>(x, csr, ptr, cnt, out);
  fused_k<<<(TILES + WPB - 1) / WPB, 512, 0, stream>>>(x, Wl, bl, Wr, cnt, out);
}

// Round 3
// 179.888 us; speedup vs baseline: 15.5223x; 2.0583x over previous
//
#include <hip/hip_runtime.h>
#include <hip/hip_bf16.h>

#define N_NODES 100000
#define N_EDGES 1600000
#define D 128
#define TILES (N_NODES / 16)   // 6250 row-tiles of 16
#define WPB 8                  // waves per block in fused kernel
#define NBKT 196               // buckets = dst >> 9 (100000/512)
#define NPB 512                // nodes per bucket
#define EPB 8192               // edges per partition block
#define PBLK 196               // ceil(1600000/8192)

typedef __attribute__((ext_vector_type(4))) float f32x4;
typedef __attribute__((ext_vector_type(2))) float f32x2;
typedef __attribute__((ext_vector_type(8))) short short8;
typedef __attribute__((ext_vector_type(4))) unsigned int u32x4;

// f32 -> bf16 round-to-nearest-even
static __device__ __forceinline__ unsigned short f2bf(float f) {
  unsigned u = __float_as_uint(f);
  u += 0x7fffu + ((u >> 16) & 1u);
  return (unsigned short)(u >> 16);
}

// ---- x -> bf16 copy (each thread packs 8 floats into 4 uints) ----
__global__ __launch_bounds__(256) void cvt_k(const float* __restrict__ x,
                                             unsigned* __restrict__ xh) {
  size_t i = (size_t)blockIdx.x * 256 + threadIdx.x;  // 1.6M threads exactly
  const f32x4* p = (const f32x4*)(x + i * 8);
  f32x4 v0 = p[0], v1 = p[1];
  u32x4 o;
  o[0] = ((unsigned)f2bf(v0[1]) << 16) | f2bf(v0[0]);
  o[1] = ((unsigned)f2bf(v0[3]) << 16) | f2bf(v0[2]);
  o[2] = ((unsigned)f2bf(v1[1]) << 16) | f2bf(v1[0]);
  o[3] = ((unsigned)f2bf(v1[3]) << 16) | f2bf(v1[2]);
  *(u32x4*)(xh + i * 4) = o;
}

// ---- P1: per-bucket edge counts (LDS histogram, few global atomics) ----
__global__ __launch_bounds__(256) void p1_count(const int* __restrict__ ei,
                                                int* __restrict__ gbcnt) {
  __shared__ int bh[256];
  int t = threadIdx.x;
  bh[t] = 0;
  __syncthreads();
  int base = blockIdx.x * EPB;
  int end = min(base + EPB, N_EDGES);
  for (int i = base + t; i < end; i += 256)
    atomicAdd(&bh[ei[N_EDGES + i] >> 9], 1);
  __syncthreads();
  if (t < NBKT && bh[t]) atomicAdd(&gbcnt[t], bh[t]);
}

// ---- P2: exclusive scan of bucket counts -> bko, init btail ----
__global__ __launch_bounds__(256) void p2_scan(const int* __restrict__ gbcnt,
                                               int* __restrict__ bko,
                                               int* __restrict__ btail) {
  __shared__ int s[256];
  int t = threadIdx.x;
  int v = (t < NBKT) ? gbcnt[t] : 0;
  s[t] = v;
  __syncthreads();
  for (int o = 1; o < 256; o <<= 1) {
    int u = (t >= o) ? s[t - o] : 0;
    __syncthreads();
    s[t] += u;
    __syncthreads();
  }
  if (t < NBKT) {
    int ex = s[t] - v;
    bko[t] = ex;
    btail[t] = ex;
  }
  if (t == 0) bko[NBKT] = N_EDGES;
}

// ---- P3: partition edges into bucket-contiguous code array ----
// code = (dst & 511) << 17 | src   (26 bits)
__global__ __launch_bounds__(256) void p3_part(const int* __restrict__ ei,
                                               int* __restrict__ btail,
                                               unsigned* __restrict__ part) {
  __shared__ int bh[256], lbase[256], lcur[256];
  int t = threadIdx.x;
  bh[t] = 0;
  lcur[t] = 0;
  __syncthreads();
  int base = blockIdx.x * EPB;
  int end = min(base + EPB, N_EDGES);
  for (int i = base + t; i < end; i += 256)
    atomicAdd(&bh[ei[N_EDGES + i] >> 9], 1);
  __syncthreads();
  if (t < NBKT && bh[t]) lbase[t] = atomicAdd(&btail[t], bh[t]);
  __syncthreads();
  for (int i = base + t; i < end; i += 256) {
    int dst = ei[N_EDGES + i];
    int src = ei[i];
    int b = dst >> 9;
    int idx = atomicAdd(&lcur[b], 1);
    part[lbase[b] + idx] = ((unsigned)(dst & (NPB - 1)) << 17) | (unsigned)src;
  }
}

// ---- P4: per-bucket CSR build, all node-level work via LDS atomics ----
__global__ __launch_bounds__(512) void p4_build(const unsigned* __restrict__ part,
                                                const int* __restrict__ bko,
                                                int* __restrict__ cnt,
                                                int* __restrict__ ptr,
                                                int* __restrict__ csr) {
  __shared__ int sc[512];
  __shared__ int sw[512];
  int t = threadIdx.x, b = blockIdx.x;
  int beg = bko[b], end = bko[b + 1];
  sc[t] = 0;
  __syncthreads();
  for (int i = beg + t; i < end; i += 512) atomicAdd(&sc[part[i] >> 17], 1);
  __syncthreads();
  int my = sc[t];
  for (int o = 1; o < 512; o <<= 1) {  // inclusive scan
    int u = (t >= o) ? sc[t - o] : 0;
    __syncthreads();
    sc[t] += u;
    __syncthreads();
  }
  int ex = sc[t] - my;
  int node = b * NPB + t;
  if (node < N_NODES) {
    cnt[node] = my;
    ptr[node] = beg + ex;
  }
  sw[t] = ex;
  __syncthreads();
  for (int i = beg + t; i < end; i += 512) {
    unsigned c = part[i];
    int pos = atomicAdd(&sw[c >> 17], 1);
    csr[beg + pos] = (int)(c & 0x1FFFFu);
  }
}

// ---- Gather: per-node sum (1 wave/node), bf16 or fp32 rows ----
template <bool XH>
__global__ __launch_bounds__(256) void gather_k(const float* __restrict__ x,
                                                const unsigned* __restrict__ xh,
                                                const int* __restrict__ csr,
                                                const int* __restrict__ ptr,
                                                const int* __restrict__ cnt,
                                                float* __restrict__ sums) {
  int node = blockIdx.x * 4 + (threadIdx.x >> 6);
  if (node >= N_NODES) return;
  int lane = threadIdx.x & 63;
  int base = ptr[node];
  int deg = cnt[node];
  float a0 = 0.f, a1 = 0.f, b0 = 0.f, b1 = 0.f;
  for (int c = 0; c < deg; c += 64) {
    int n = min(64, deg - c);
    int eidx = (c + lane < deg) ? csr[base + c + lane] : 0;
    int j = 0;
    for (; j + 1 < n; j += 2) {
      int s0 = __shfl(eidx, j);
      int s1 = __shfl(eidx, j + 1);
      if (XH) {
        unsigned u0 = xh[(size_t)s0 * 64 + lane];
        unsigned u1 = xh[(size_t)s1 * 64 + lane];
        a0 += __uint_as_float(u0 << 16);
        a1 += __uint_as_float(u0 & 0xffff0000u);
        b0 += __uint_as_float(u1 << 16);
        b1 += __uint_as_float(u1 & 0xffff0000u);
      } else {
        f32x2 v0 = *(const f32x2*)(x + (size_t)s0 * D + lane * 2);
        f32x2 v1 = *(const f32x2*)(x + (size_t)s1 * D + lane * 2);
        a0 += v0[0]; a1 += v0[1];
        b0 += v1[0]; b1 += v1[1];
      }
    }
    if (j < n) {
      int s0 = __shfl(eidx, j);
      if (XH) {
        unsigned u0 = xh[(size_t)s0 * 64 + lane];
        a0 += __uint_as_float(u0 << 16);
        a1 += __uint_as_float(u0 & 0xffff0000u);
      } else {
        f32x2 v0 = *(const f32x2*)(x + (size_t)s0 * D + lane * 2);
        a0 += v0[0]; a1 += v0[1];
      }
    }
  }
  f32x2 r;
  r[0] = a0 + b0;
  r[1] = a1 + b1;
  *(f32x2*)(sums + (size_t)node * D + lane * 2) = r;
}

// ---- Fused: out = normalize( [sums*inv | x] @ [W_l; W_r] + b_l ), bf16 MFMA ----
template <bool XH>
__global__ __launch_bounds__(512) void fused_k(
    const float* __restrict__ x, const unsigned* __restrict__ xh,
    const float* __restrict__ Wl, const float* __restrict__ bl,
    const float* __restrict__ Wr, const int* __restrict__ cnt,
    float* __restrict__ out /* in: sums, out: result */) {
  __shared__ unsigned short Wt[128 * 256];  // 64 KiB

  int tid = threadIdx.x;
  for (int i = tid; i < 128 * 256; i += 512) {
    int k = i >> 7;       // 0..255 (0..127 = W_l rows, 128..255 = W_r rows)
    int c = i & 127;      // output column
    float w = (k < 128) ? Wl[k * 128 + c] : Wr[(k - 128) * 128 + c];
    int phys = (k >> 3) ^ (c & 7);  // swizzle 16B chunk index within the row
    Wt[c * 256 + (phys << 3) + (k & 7)] = f2bf(w);
  }
  __syncthreads();

  int tile = blockIdx.x * WPB + (tid >> 6);
  if (tile >= TILES) return;
  int lane = tid & 63;
  int c0 = lane & 15;  // A-row within tile / D-column-within-16
  int g = lane >> 4;   // k-group selector
  int row0 = tile * 16;

  float cv = (float)cnt[row0 + c0];
  float inv = 1.0f / fmaxf(cv, 1.0f);

  f32x4 acc[8];
  #pragma unroll
  for (int ct = 0; ct < 8; ct++)
    for (int j = 0; j < 4; j++) acc[ct][j] = 0.0f;

  #pragma unroll
  for (int kf = 0; kf < 8; kf++) {
    int koff = (kf & 3) * 32 + g * 8;
    short8 af;
    if (kf >= 4 && XH) {
      af = *(const short8*)((const unsigned short*)xh +
                            (size_t)(row0 + c0) * D + koff);
    } else {
      const float* a_src = (kf < 4) ? out : x;
      float s = (kf < 4) ? inv : 1.0f;
      const float* p = a_src + (size_t)(row0 + c0) * D + koff;
      f32x4 v0 = *(const f32x4*)p;
      f32x4 v1 = *(const f32x4*)(p + 4);
      af[0] = (short)f2bf(v0[0] * s);
      af[1] = (short)f2bf(v0[1] * s);
      af[2] = (short)f2bf(v0[2] * s);
      af[3] = (short)f2bf(v0[3] * s);
      af[4] = (short)f2bf(v1[0] * s);
      af[5] = (short)f2bf(v1[1] * s);
      af[6] = (short)f2bf(v1[2] * s);
      af[7] = (short)f2bf(v1[3] * s);
    }
    #pragma unroll
    for (int ct = 0; ct < 8; ct++) {
      int c = ct * 16 + c0;
      short8 bf = *(const short8*)&Wt[c * 256 + ((((kf << 2) + g) ^ (c & 7)) << 3)];
      acc[ct] = __builtin_amdgcn_mfma_f32_16x16x32_bf16(af, bf, acc[ct], 0, 0, 0);
    }
  }

  // Epilogue: + bias, row L2-normalize (D layout: col = lane&15, row = g*4+j).
  float ss[4] = {0.f, 0.f, 0.f, 0.f};
  #pragma unroll
  for (int ct = 0; ct < 8; ct++) {
    float bias = bl[ct * 16 + c0];
    #pragma unroll
    for (int j = 0; j < 4; j++) {
      float v = acc[ct][j] + bias;
      acc[ct][j] = v;
      ss[j] += v * v;
    }
  }
  #pragma unroll
  for (int j = 0; j < 4; j++) {
    float s = ss[j];
    s += __shfl_xor(s, 1);
    s += __shfl_xor(s, 2);
    s += __shfl_xor(s, 4);
    s += __shfl_xor(s, 8);
    ss[j] = 1.0f / fmaxf(sqrtf(s), 1e-12f);
  }
  #pragma unroll
  for (int ct = 0; ct < 8; ct++) {
    #pragma unroll
    for (int j = 0; j < 4; j++) {
      out[(size_t)(row0 + g * 4 + j) * D + ct * 16 + c0] = acc[ct][j] * ss[j];
    }
  }
}

extern "C" void kernel_launch(void* const* d_in, const int* in_sizes, int n_in,
                              void* d_out, int out_size, void* d_ws, size_t ws_size,
                              hipStream_t stream) {
  const float* x  = (const float*)d_in[0];
  const int*   ei = (const int*)d_in[1];
  const float* Wl = (const float*)d_in[2];
  const float* bl = (const float*)d_in[3];
  const float* Wr = (const float*)d_in[4];
  float* out = (float*)d_out;

  // Workspace layout (int elements)
  int* w = (int*)d_ws;
  int* cnt   = w;                      // 100000
  int* ptr   = w + 100000;             // 100000
  int* gbcnt = w + 200000;             // 256
  int* bko   = w + 200256;             // 257
  int* btail = w + 200520;             // 256
  unsigned* part = (unsigned*)(w + 200800);  // 1600000
  int* csr   = w + 1800800;            // 1600000  (13.6 MB so far)
  const size_t XH_OFF = 3400800ULL * 4;      // 13603200, 64B aligned
  unsigned* xh = (unsigned*)((char*)d_ws + XH_OFF);  // 25.6 MB bf16 x
  bool use_xh = ws_size >= XH_OFF + (size_t)N_NODES * D * 2;

  hipMemsetAsync(gbcnt, 0, 256 * sizeof(int), stream);
  if (use_xh) cvt_k<<<6250, 256, 0, stream>>>(x, xh);
  p1_count<<<PBLK, 256, 0, stream>>>(ei, gbcnt);
  p2_scan<<<1, 256, 0, stream>>>(gbcnt, bko, btail);
  p3_part<<<PBLK, 256, 0, stream>>>(ei, btail, part);
  p4_build<<<NBKT, 512, 0, stream>>>(part, bko, cnt, ptr, csr);

  if (use_xh) {
    gather_k<true><<<(N_NODES + 3) / 4, 256, 0, stream>>>(x, xh, csr, ptr, cnt, out);
    fused_k<true><<<(TILES + WPB - 1) / WPB, 512, 0, stream>>>(x, xh, Wl, bl, Wr, cnt, out);
  } else {
    gather_k<false><<<(N_NODES + 3) / 4, 256, 0, stream>>>(x, xh, csr, ptr, cnt, out);
    fused_k<false><<<(TILES + WPB - 1) / WPB, 512, 0, stream>>>(x, xh, Wl, bl, Wr, cnt, out);
  }
}

// Round 4
// 160.612 us; speedup vs baseline: 17.3851x; 1.1200x over previous
//
#include <hip/hip_runtime.h>
#include <hip/hip_bf16.h>

#define N_NODES 100000
#define N_EDGES 1600000
#define D 128
#define TILES (N_NODES / 16)   // 6250 row-tiles of 16
#define WPB 8                  // waves per block in fused kernel
#define NBKT 196               // buckets = dst >> 9 (100000/512)
#define NPB 512                // nodes per bucket
#define EPB 8192               // edges per partition block
#define PBLK 196               // ceil(1600000/8192)

typedef __attribute__((ext_vector_type(4))) float f32x4;
typedef __attribute__((ext_vector_type(2))) float f32x2;
typedef __attribute__((ext_vector_type(8))) short short8;
typedef __attribute__((ext_vector_type(4))) unsigned int u32x4;
typedef __attribute__((ext_vector_type(2))) unsigned int u32x2;

// f32 -> bf16 round-to-nearest-even
static __device__ __forceinline__ unsigned short f2bf(float f) {
  unsigned u = __float_as_uint(f);
  u += 0x7fffu + ((u >> 16) & 1u);
  return (unsigned short)(u >> 16);
}

static __device__ __forceinline__ void acc4(u32x2 u, float& a0, float& a1,
                                            float& a2, float& a3) {
  a0 += __uint_as_float(u[0] << 16);
  a1 += __uint_as_float(u[0] & 0xffff0000u);
  a2 += __uint_as_float(u[1] << 16);
  a3 += __uint_as_float(u[1] & 0xffff0000u);
}

// ---- x -> bf16 copy (each thread packs 8 floats into 4 uints) ----
__global__ __launch_bounds__(256) void cvt_k(const float* __restrict__ x,
                                             unsigned* __restrict__ xh) {
  size_t i = (size_t)blockIdx.x * 256 + threadIdx.x;  // 1.6M threads exactly
  const f32x4* p = (const f32x4*)(x + i * 8);
  f32x4 v0 = p[0], v1 = p[1];
  u32x4 o;
  o[0] = ((unsigned)f2bf(v0[1]) << 16) | f2bf(v0[0]);
  o[1] = ((unsigned)f2bf(v0[3]) << 16) | f2bf(v0[2]);
  o[2] = ((unsigned)f2bf(v1[1]) << 16) | f2bf(v1[0]);
  o[3] = ((unsigned)f2bf(v1[3]) << 16) | f2bf(v1[2]);
  *(u32x4*)(xh + i * 4) = o;
}

// ---- P1: per-bucket edge counts (LDS histogram, few global atomics) ----
__global__ __launch_bounds__(256) void p1_count(const int* __restrict__ ei,
                                                int* __restrict__ gbcnt) {
  __shared__ int bh[256];
  int t = threadIdx.x;
  bh[t] = 0;
  __syncthreads();
  int base = blockIdx.x * EPB;
  int end = min(base + EPB, N_EDGES);
  for (int i = base + t; i < end; i += 256)
    atomicAdd(&bh[ei[N_EDGES + i] >> 9], 1);
  __syncthreads();
  if (t < NBKT && bh[t]) atomicAdd(&gbcnt[t], bh[t]);
}

// ---- P2: exclusive scan of bucket counts -> bko, init btail ----
__global__ __launch_bounds__(256) void p2_scan(const int* __restrict__ gbcnt,
                                               int* __restrict__ bko,
                                               int* __restrict__ btail) {
  __shared__ int s[256];
  int t = threadIdx.x;
  int v = (t < NBKT) ? gbcnt[t] : 0;
  s[t] = v;
  __syncthreads();
  for (int o = 1; o < 256; o <<= 1) {
    int u = (t >= o) ? s[t - o] : 0;
    __syncthreads();
    s[t] += u;
    __syncthreads();
  }
  if (t < NBKT) {
    int ex = s[t] - v;
    bko[t] = ex;
    btail[t] = ex;
  }
  if (t == 0) bko[NBKT] = N_EDGES;
}

// ---- P3: partition edges into bucket-contiguous code array ----
// code = (dst & 511) << 17 | src   (26 bits)
__global__ __launch_bounds__(256) void p3_part(const int* __restrict__ ei,
                                               int* __restrict__ btail,
                                               unsigned* __restrict__ part) {
  __shared__ int bh[256], lbase[256], lcur[256];
  int t = threadIdx.x;
  bh[t] = 0;
  lcur[t] = 0;
  __syncthreads();
  int base = blockIdx.x * EPB;
  int end = min(base + EPB, N_EDGES);
  for (int i = base + t; i < end; i += 256)
    atomicAdd(&bh[ei[N_EDGES + i] >> 9], 1);
  __syncthreads();
  if (t < NBKT && bh[t]) lbase[t] = atomicAdd(&btail[t], bh[t]);
  __syncthreads();
  for (int i = base + t; i < end; i += 256) {
    int dst = ei[N_EDGES + i];
    int src = ei[i];
    int b = dst >> 9;
    int idx = atomicAdd(&lcur[b], 1);
    part[lbase[b] + idx] = ((unsigned)(dst & (NPB - 1)) << 17) | (unsigned)src;
  }
}

// ---- P4: per-bucket CSR build, all node-level work via LDS atomics ----
__global__ __launch_bounds__(512) void p4_build(const unsigned* __restrict__ part,
                                                const int* __restrict__ bko,
                                                int* __restrict__ cnt,
                                                int* __restrict__ ptr,
                                                int* __restrict__ csr) {
  __shared__ int sc[512];
  __shared__ int sw[512];
  int t = threadIdx.x, b = blockIdx.x;
  int beg = bko[b], end = bko[b + 1];
  sc[t] = 0;
  __syncthreads();
  for (int i = beg + t; i < end; i += 512) atomicAdd(&sc[part[i] >> 17], 1);
  __syncthreads();
  int my = sc[t];
  for (int o = 1; o < 512; o <<= 1) {  // inclusive scan
    int u = (t >= o) ? sc[t - o] : 0;
    __syncthreads();
    sc[t] += u;
    __syncthreads();
  }
  int ex = sc[t] - my;
  int node = b * NPB + t;
  if (node < N_NODES) {
    cnt[node] = my;
    ptr[node] = beg + ex;
  }
  sw[t] = ex;
  __syncthreads();
  for (int i = beg + t; i < end; i += 512) {
    unsigned c = part[i];
    int pos = atomicAdd(&sw[c >> 17], 1);
    csr[beg + pos] = (int)(c & 0x1FFFFu);
  }
}

// ---- Gather v2: 2 nodes/wave, 32 lanes x 4 dims, 4-deep unroll ----
// Reads bf16 x rows, writes bf16 MEAN (inv applied here).
__global__ __launch_bounds__(256) void gather2_k(const unsigned* __restrict__ xh,
                                                 const int* __restrict__ csr,
                                                 const int* __restrict__ ptr,
                                                 const int* __restrict__ cnt,
                                                 unsigned* __restrict__ mh) {
  int wid = (blockIdx.x * 256 + threadIdx.x) >> 6;
  int lane = threadIdx.x & 63;
  int half = lane >> 5, lh = lane & 31;
  int node = wid * 2 + half;
  if (node >= N_NODES) return;
  int base = ptr[node];
  int deg = cnt[node];
  float a0 = 0.f, a1 = 0.f, a2 = 0.f, a3 = 0.f;
  float b0 = 0.f, b1 = 0.f, b2 = 0.f, b3 = 0.f;
  for (int c = 0; c < deg; c += 32) {
    int rem = deg - c;
    int n = min(32, rem);
    int eidx = (lh < rem) ? csr[base + c + lh] : 0;
    int j = 0;
    for (; j + 3 < n; j += 4) {
      int s0 = __shfl(eidx, j, 32);
      int s1 = __shfl(eidx, j + 1, 32);
      int s2 = __shfl(eidx, j + 2, 32);
      int s3 = __shfl(eidx, j + 3, 32);
      u32x2 u0 = *(const u32x2*)(xh + (size_t)s0 * 64 + lh * 2);
      u32x2 u1 = *(const u32x2*)(xh + (size_t)s1 * 64 + lh * 2);
      u32x2 u2 = *(const u32x2*)(xh + (size_t)s2 * 64 + lh * 2);
      u32x2 u3 = *(const u32x2*)(xh + (size_t)s3 * 64 + lh * 2);
      acc4(u0, a0, a1, a2, a3);
      acc4(u1, b0, b1, b2, b3);
      acc4(u2, a0, a1, a2, a3);
      acc4(u3, b0, b1, b2, b3);
    }
    for (; j < n; j++) {
      int s0 = __shfl(eidx, j, 32);
      u32x2 u0 = *(const u32x2*)(xh + (size_t)s0 * 64 + lh * 2);
      acc4(u0, a0, a1, a2, a3);
    }
  }
  float inv = 1.0f / fmaxf((float)deg, 1.0f);
  a0 = (a0 + b0) * inv;
  a1 = (a1 + b1) * inv;
  a2 = (a2 + b2) * inv;
  a3 = (a3 + b3) * inv;
  u32x2 o;
  o[0] = ((unsigned)f2bf(a1) << 16) | f2bf(a0);
  o[1] = ((unsigned)f2bf(a3) << 16) | f2bf(a2);
  *(u32x2*)(mh + (size_t)node * 64 + lh * 2) = o;
}

// ---- Gather fallback (R3): 1 wave/node, f32 sums into out ----
template <bool XH>
__global__ __launch_bounds__(256) void gather_k(const float* __restrict__ x,
                                                const unsigned* __restrict__ xh,
                                                const int* __restrict__ csr,
                                                const int* __restrict__ ptr,
                                                const int* __restrict__ cnt,
                                                float* __restrict__ sums) {
  int node = blockIdx.x * 4 + (threadIdx.x >> 6);
  if (node >= N_NODES) return;
  int lane = threadIdx.x & 63;
  int base = ptr[node];
  int deg = cnt[node];
  float a0 = 0.f, a1 = 0.f, b0 = 0.f, b1 = 0.f;
  for (int c = 0; c < deg; c += 64) {
    int n = min(64, deg - c);
    int eidx = (c + lane < deg) ? csr[base + c + lane] : 0;
    int j = 0;
    for (; j + 1 < n; j += 2) {
      int s0 = __shfl(eidx, j);
      int s1 = __shfl(eidx, j + 1);
      if (XH) {
        unsigned u0 = xh[(size_t)s0 * 64 + lane];
        unsigned u1 = xh[(size_t)s1 * 64 + lane];
        a0 += __uint_as_float(u0 << 16);
        a1 += __uint_as_float(u0 & 0xffff0000u);
        b0 += __uint_as_float(u1 << 16);
        b1 += __uint_as_float(u1 & 0xffff0000u);
      } else {
        f32x2 v0 = *(const f32x2*)(x + (size_t)s0 * D + lane * 2);
        f32x2 v1 = *(const f32x2*)(x + (size_t)s1 * D + lane * 2);
        a0 += v0[0]; a1 += v0[1];
        b0 += v1[0]; b1 += v1[1];
      }
    }
    if (j < n) {
      int s0 = __shfl(eidx, j);
      if (XH) {
        unsigned u0 = xh[(size_t)s0 * 64 + lane];
        a0 += __uint_as_float(u0 << 16);
        a1 += __uint_as_float(u0 & 0xffff0000u);
      } else {
        f32x2 v0 = *(const f32x2*)(x + (size_t)s0 * D + lane * 2);
        a0 += v0[0]; a1 += v0[1];
      }
    }
  }
  f32x2 r;
  r[0] = a0 + b0;
  r[1] = a1 + b1;
  *(f32x2*)(sums + (size_t)node * D + lane * 2) = r;
}

// ---- Fused: out = normalize( [mean | x] @ [W_l; W_r] + b_l ), bf16 MFMA ----
// AMODE 0: mean from f32 sums in `out` (scale by inv), x from f32
// AMODE 1: mean from f32 sums in `out` (scale by inv), x from xh
// AMODE 2: mean from bf16 mh, x from xh
template <int AMODE>
__global__ __launch_bounds__(512) void fused_k(
    const float* __restrict__ x, const unsigned* __restrict__ xh,
    const unsigned* __restrict__ mh, const float* __restrict__ Wl,
    const float* __restrict__ bl, const float* __restrict__ Wr,
    const int* __restrict__ cnt, float* __restrict__ out) {
  __shared__ unsigned short Wt[128 * 256];  // 64 KiB

  int tid = threadIdx.x;
  for (int i = tid; i < 128 * 256; i += 512) {
    int k = i >> 7;       // 0..255 (0..127 = W_l rows, 128..255 = W_r rows)
    int c = i & 127;      // output column
    float w = (k < 128) ? Wl[k * 128 + c] : Wr[(k - 128) * 128 + c];
    int phys = (k >> 3) ^ (c & 7);  // swizzle 16B chunk index within the row
    Wt[c * 256 + (phys << 3) + (k & 7)] = f2bf(w);
  }
  __syncthreads();

  int tile = blockIdx.x * WPB + (tid >> 6);
  if (tile >= TILES) return;
  int lane = tid & 63;
  int c0 = lane & 15;  // A-row within tile / D-column-within-16
  int g = lane >> 4;   // k-group selector
  int row0 = tile * 16;

  float inv = 1.0f;
  if (AMODE < 2) inv = 1.0f / fmaxf((float)cnt[row0 + c0], 1.0f);

  f32x4 acc[8];
  #pragma unroll
  for (int ct = 0; ct < 8; ct++)
    for (int j = 0; j < 4; j++) acc[ct][j] = 0.0f;

  #pragma unroll
  for (int kf = 0; kf < 8; kf++) {
    int koff = (kf & 3) * 32 + g * 8;
    short8 af;
    if (kf < 4 && AMODE == 2) {
      af = *(const short8*)((const unsigned short*)mh +
                            (size_t)(row0 + c0) * D + koff);
    } else if (kf >= 4 && AMODE >= 1) {
      af = *(const short8*)((const unsigned short*)xh +
                            (size_t)(row0 + c0) * D + koff);
    } else {
      const float* a_src = (kf < 4) ? out : x;
      float s = (kf < 4) ? inv : 1.0f;
      const float* p = a_src + (size_t)(row0 + c0) * D + koff;
      f32x4 v0 = *(const f32x4*)p;
      f32x4 v1 = *(const f32x4*)(p + 4);
      af[0] = (short)f2bf(v0[0] * s);
      af[1] = (short)f2bf(v0[1] * s);
      af[2] = (short)f2bf(v0[2] * s);
      af[3] = (short)f2bf(v0[3] * s);
      af[4] = (short)f2bf(v1[0] * s);
      af[5] = (short)f2bf(v1[1] * s);
      af[6] = (short)f2bf(v1[2] * s);
      af[7] = (short)f2bf(v1[3] * s);
    }
    #pragma unroll
    for (int ct = 0; ct < 8; ct++) {
      int c = ct * 16 + c0;
      short8 bf = *(const short8*)&Wt[c * 256 + ((((kf << 2) + g) ^ (c & 7)) << 3)];
      acc[ct] = __builtin_amdgcn_mfma_f32_16x16x32_bf16(af, bf, acc[ct], 0, 0, 0);
    }
  }

  // Epilogue: + bias, row L2-normalize (D layout: col = lane&15, row = g*4+j).
  float ss[4] = {0.f, 0.f, 0.f, 0.f};
  #pragma unroll
  for (int ct = 0; ct < 8; ct++) {
    float bias = bl[ct * 16 + c0];
    #pragma unroll
    for (int j = 0; j < 4; j++) {
      float v = acc[ct][j] + bias;
      acc[ct][j] = v;
      ss[j] += v * v;
    }
  }
  #pragma unroll
  for (int j = 0; j < 4; j++) {
    float s = ss[j];
    s += __shfl_xor(s, 1);
    s += __shfl_xor(s, 2);
    s += __shfl_xor(s, 4);
    s += __shfl_xor(s, 8);
    ss[j] = 1.0f / fmaxf(sqrtf(s), 1e-12f);
  }
  #pragma unroll
  for (int ct = 0; ct < 8; ct++) {
    #pragma unroll
    for (int j = 0; j < 4; j++) {
      out[(size_t)(row0 + g * 4 + j) * D + ct * 16 + c0] = acc[ct][j] * ss[j];
    }
  }
}

extern "C" void kernel_launch(void* const* d_in, const int* in_sizes, int n_in,
                              void* d_out, int out_size, void* d_ws, size_t ws_size,
                              hipStream_t stream) {
  const float* x  = (const float*)d_in[0];
  const int*   ei = (const int*)d_in[1];
  const float* Wl = (const float*)d_in[2];
  const float* bl = (const float*)d_in[3];
  const float* Wr = (const float*)d_in[4];
  float* out = (float*)d_out;

  // Workspace layout (int elements)
  int* w = (int*)d_ws;
  int* cnt   = w;                      // 100000
  int* ptr   = w + 100000;             // 100000
  int* gbcnt = w + 200000;             // 256
  int* bko   = w + 200256;             // 257
  int* btail = w + 200520;             // 256
  unsigned* part = (unsigned*)(w + 200800);  // 1600000
  int* csr   = w + 1800800;            // 1600000  (13.6 MB so far)
  const size_t XH_OFF = 3400800ULL * 4;       // 13603200 B, 16B aligned
  const size_t MH_OFF = XH_OFF + (size_t)N_NODES * D * 2;  // +25.6 MB
  unsigned* xh = (unsigned*)((char*)d_ws + XH_OFF);
  unsigned* mh = (unsigned*)((char*)d_ws + MH_OFF);
  bool use_xh = ws_size >= MH_OFF;
  bool use_mh = ws_size >= MH_OFF + (size_t)N_NODES * D * 2;

  hipMemsetAsync(gbcnt, 0, 256 * sizeof(int), stream);
  if (use_xh) cvt_k<<<6250, 256, 0, stream>>>(x, xh);
  p1_count<<<PBLK, 256, 0, stream>>>(ei, gbcnt);
  p2_scan<<<1, 256, 0, stream>>>(gbcnt, bko, btail);
  p3_part<<<PBLK, 256, 0, stream>>>(ei, btail, part);
  p4_build<<<NBKT, 512, 0, stream>>>(part, bko, cnt, ptr, csr);

  if (use_mh) {
    gather2_k<<<12500, 256, 0, stream>>>(xh, csr, ptr, cnt, mh);
    fused_k<2><<<(TILES + WPB - 1) / WPB, 512, 0, stream>>>(x, xh, mh, Wl, bl, Wr, cnt, out);
  } else if (use_xh) {
    gather_k<true><<<(N_NODES + 3) / 4, 256, 0, stream>>>(x, xh, csr, ptr, cnt, out);
    fused_k<1><<<(TILES + WPB - 1) / WPB, 512, 0, stream>>>(x, xh, mh, Wl, bl, Wr, cnt, out);
  } else {
    gather_k<false><<<(N_NODES + 3) / 4, 256, 0, stream>>>(x, xh, csr, ptr, cnt, out);
    fused_k<0><<<(TILES + WPB - 1) / WPB, 512, 0, stream>>>(x, xh, mh, Wl, bl, Wr, cnt, out);
  }
}